// Round 4
// baseline (417.416 us; speedup 1.0000x reference)
//
#include <hip/hip_runtime.h>

#define D 128
#define AGG_CAP 96   // LDS-staged ids per node; deg>CAP handled by direct tail

typedef __attribute__((ext_vector_type(8))) short short8;
typedef __attribute__((ext_vector_type(4))) float floatx4;

__device__ __forceinline__ short f32_bf16(float f) {
    unsigned u = __builtin_bit_cast(unsigned, f);
    u += 0x7fffu + ((u >> 16) & 1u);          // RNE
    return (short)(u >> 16);
}

// physical XCD id (hwreg 20 = HW_REG_XCC_ID, bits [3:0]) — wave-uniform
__device__ __forceinline__ int xcd_id() {
    return __builtin_amdgcn_s_getreg(20 | (3 << 11)) & 7;
}

__device__ __forceinline__ void wg_add(int* p) {
    __hip_atomic_fetch_add(p, 1, __ATOMIC_RELAXED, __HIP_MEMORY_SCOPE_WORKGROUP);
}

// ---------------------------------------------------------------------------
// K1: BOTH degree histograms in one E-scan. Per-XCD replicas + workgroup-scope
// atomics (serviced in the local L2; exact under any block->XCD placement).
// ---------------------------------------------------------------------------
__global__ __launch_bounds__(256) void k_hist(const int* __restrict__ src,
                                              const int* __restrict__ dst,
                                              int* __restrict__ out_rep,
                                              int* __restrict__ in_rep,
                                              int E, int N) {
    const int r = xcd_id();
    const int t = blockIdx.x * 256 + threadIdx.x;
    const int nv = E >> 2;
    if (t < nv) {
        int4 s = ((const int4*)src)[t];
        int4 d = ((const int4*)dst)[t];
        wg_add(&out_rep[r * N + s.x]); wg_add(&in_rep[r * N + d.x]);
        wg_add(&out_rep[r * N + s.y]); wg_add(&in_rep[r * N + d.y]);
        wg_add(&out_rep[r * N + s.z]); wg_add(&in_rep[r * N + d.z]);
        wg_add(&out_rep[r * N + s.w]); wg_add(&in_rep[r * N + d.w]);
    }
    int e = (nv << 2) + t;
    if (e < E) {
        wg_add(&out_rep[r * N + src[e]]);
        wg_add(&in_rep[r * N + dst[e]]);
    }
}

// ---------------------------------------------------------------------------
// K2: dense CSR base allocation. Reduce in-degree replicas, block-level
// inclusive scan (LDS), one global atomicAdd per block -> exact, disjoint,
// unordered base offsets (order irrelevant: agg reads base[n]+deg[n]).
// Also emits deg[n] and norm_src[n] (from out-degree replicas).
// ---------------------------------------------------------------------------
__global__ __launch_bounds__(256) void k_base(const int* __restrict__ in_rep,
                                              const int* __restrict__ out_rep,
                                              int* __restrict__ base,
                                              int* __restrict__ deg,
                                              float* __restrict__ nsrc,
                                              int* __restrict__ total,
                                              int N) {
    __shared__ int sc[256];
    __shared__ int b0;
    const int tid = threadIdx.x;
    const int i = blockIdx.x * 256 + tid;
    int dg = 0;
    if (i < N) {
        #pragma unroll
        for (int r = 0; r < 8; ++r) dg += in_rep[r * N + i];
    }
    sc[tid] = dg;
    __syncthreads();
    #pragma unroll
    for (int off = 1; off < 256; off <<= 1) {
        int v = (tid >= off) ? sc[tid - off] : 0;
        __syncthreads();
        sc[tid] += v;
        __syncthreads();
    }
    if (tid == 255) b0 = atomicAdd(total, sc[255]);
    __syncthreads();
    if (i < N) {
        base[i] = b0 + sc[tid] - dg;   // exclusive position within block
        deg[i]  = dg;
        int og = 0;
        #pragma unroll
        for (int r = 0; r < 8; ++r) og += out_rep[r * N + i];
        nsrc[i] = rsqrtf((float)max(og, 1));
    }
}

// ---------------------------------------------------------------------------
// K3: x -> bf16 copy (halves k_agg gather traffic)
// ---------------------------------------------------------------------------
__global__ __launch_bounds__(256) void k_cvt(const float* __restrict__ x,
                                             unsigned short* __restrict__ xb,
                                             int n8) {
    int i = blockIdx.x * 256 + threadIdx.x;
    if (i < n8) {
        float4 a = ((const float4*)x)[2 * i];
        float4 b = ((const float4*)x)[2 * i + 1];
        short8 v;
        v[0] = f32_bf16(a.x); v[1] = f32_bf16(a.y);
        v[2] = f32_bf16(a.z); v[3] = f32_bf16(a.w);
        v[4] = f32_bf16(b.x); v[5] = f32_bf16(b.y);
        v[6] = f32_bf16(b.z); v[7] = f32_bf16(b.w);
        *(short8*)(xb + i * 8) = v;
    }
}

// ---------------------------------------------------------------------------
// K4: dense-CSR scatter, SINGLE E-scan, no windowing. Cross-XCD merging of
// 4B payload writes into shared 64B lines is delegated to the LLC via
// agent-scope atomics (the coherence point), so: packed payload = 6.4 MB of
// writeback instead of the replica-ELL layout's ~51 MB line floor, and no
// multi-pass edge re-reads. Slot counters agent-scope for exactness.
// ---------------------------------------------------------------------------
__device__ __forceinline__ void scat1(int d, int s,
                                      const int* __restrict__ base,
                                      int* __restrict__ wcnt,
                                      int* __restrict__ csr) {
    int slot = __hip_atomic_fetch_add(&wcnt[d], 1, __ATOMIC_RELAXED,
                                      __HIP_MEMORY_SCOPE_AGENT);
    __hip_atomic_store(&csr[base[d] + slot], s, __ATOMIC_RELAXED,
                       __HIP_MEMORY_SCOPE_AGENT);
}

__global__ __launch_bounds__(256) void k_scatter(const int* __restrict__ src,
                                                 const int* __restrict__ dst,
                                                 const int* __restrict__ base,
                                                 int* __restrict__ wcnt,
                                                 int* __restrict__ csr, int E) {
    const int t = blockIdx.x * 256 + threadIdx.x;
    const int nv = E >> 2;
    if (t < nv) {
        int4 d4 = ((const int4*)dst)[t];
        int4 s4 = ((const int4*)src)[t];
        scat1(d4.x, s4.x, base, wcnt, csr);
        scat1(d4.y, s4.y, base, wcnt, csr);
        scat1(d4.z, s4.z, base, wcnt, csr);
        scat1(d4.w, s4.w, base, wcnt, csr);
    }
    int e = (nv << 2) + t;
    if (e < E) scat1(dst[e], src[e], base, wcnt, csr);
}

// ---------------------------------------------------------------------------
// K5: per-node aggregation over DENSE rows: ids = csr[base[n] .. base[n]+deg).
// One wave per node; stage first min(deg,CAP) ids into LDS (wave-uniform
// broadcast reads), unroll-4 gather loop; rare deg>CAP tail reads csr direct
// (uniform address -> single broadcast fetch per id).
// ---------------------------------------------------------------------------
__global__ __launch_bounds__(256) void k_agg(const int* __restrict__ csr,
                                             const int* __restrict__ base,
                                             const int* __restrict__ deg,
                                             const float* __restrict__ norm_src,
                                             const unsigned int* __restrict__ xb,
                                             const float* __restrict__ x,
                                             float* __restrict__ agg, int N) {
    __shared__ int ids_s[4][AGG_CAP];
    const int w = threadIdx.x >> 6;
    const int lane = threadIdx.x & 63;
    int n = blockIdx.x * 4 + w;
    if (n >= N) n = N - 1;              // duplicate work; keeps barriers uniform

    const int dg = deg[n];
    const int bs = base[n];
    const int mm = min(dg, AGG_CAP);

    #pragma unroll
    for (int j = 0; j < (AGG_CAP + 63) / 64; ++j) {
        int idx = lane + j * 64;
        if (idx < mm) ids_s[w][idx] = csr[bs + idx];
    }
    __syncthreads();

    const int* ids = ids_s[w];
    float ax = 0.f, ay = 0.f;
    if (xb) {
        int i = 0;
        for (; i + 4 <= mm; i += 4) {
            int s0 = ids[i];
            int s1 = ids[i + 1];
            int s2 = ids[i + 2];
            int s3 = ids[i + 3];
            float a0 = norm_src[s0];
            float a1 = norm_src[s1];
            float a2 = norm_src[s2];
            float a3 = norm_src[s3];
            unsigned u0 = xb[s0 * 64 + lane];
            unsigned u1 = xb[s1 * 64 + lane];
            unsigned u2 = xb[s2 * 64 + lane];
            unsigned u3 = xb[s3 * 64 + lane];
            ax = fmaf(__builtin_bit_cast(float, u0 << 16), a0, ax);
            ay = fmaf(__builtin_bit_cast(float, u0 & 0xffff0000u), a0, ay);
            ax = fmaf(__builtin_bit_cast(float, u1 << 16), a1, ax);
            ay = fmaf(__builtin_bit_cast(float, u1 & 0xffff0000u), a1, ay);
            ax = fmaf(__builtin_bit_cast(float, u2 << 16), a2, ax);
            ay = fmaf(__builtin_bit_cast(float, u2 & 0xffff0000u), a2, ay);
            ax = fmaf(__builtin_bit_cast(float, u3 << 16), a3, ax);
            ay = fmaf(__builtin_bit_cast(float, u3 & 0xffff0000u), a3, ay);
        }
        for (; i < mm; ++i) {
            int s0 = ids[i];
            float a0 = norm_src[s0];
            unsigned u0 = xb[s0 * 64 + lane];
            ax = fmaf(__builtin_bit_cast(float, u0 << 16), a0, ax);
            ay = fmaf(__builtin_bit_cast(float, u0 & 0xffff0000u), a0, ay);
        }
        for (int k = mm; k < dg; ++k) {          // deg>CAP tail (rare)
            int s0 = csr[bs + k];
            float a0 = norm_src[s0];
            unsigned u0 = xb[s0 * 64 + lane];
            ax = fmaf(__builtin_bit_cast(float, u0 << 16), a0, ax);
            ay = fmaf(__builtin_bit_cast(float, u0 & 0xffff0000u), a0, ay);
        }
    } else {
        const float2* __restrict__ x2 = (const float2*)x;
        int i = 0;
        for (; i + 4 <= mm; i += 4) {
            int s0 = ids[i];
            int s1 = ids[i + 1];
            int s2 = ids[i + 2];
            int s3 = ids[i + 3];
            float a0 = norm_src[s0];
            float a1 = norm_src[s1];
            float a2 = norm_src[s2];
            float a3 = norm_src[s3];
            float2 v0 = x2[s0 * 64 + lane];
            float2 v1 = x2[s1 * 64 + lane];
            float2 v2 = x2[s2 * 64 + lane];
            float2 v3 = x2[s3 * 64 + lane];
            ax = fmaf(v0.x, a0, ax); ay = fmaf(v0.y, a0, ay);
            ax = fmaf(v1.x, a1, ax); ay = fmaf(v1.y, a1, ay);
            ax = fmaf(v2.x, a2, ax); ay = fmaf(v2.y, a2, ay);
            ax = fmaf(v3.x, a3, ax); ay = fmaf(v3.y, a3, ay);
        }
        for (; i < mm; ++i) {
            int s0 = ids[i];
            float a0 = norm_src[s0];
            float2 v0 = x2[s0 * 64 + lane];
            ax = fmaf(v0.x, a0, ax); ay = fmaf(v0.y, a0, ay);
        }
        for (int k = mm; k < dg; ++k) {
            int s0 = csr[bs + k];
            float a0 = norm_src[s0];
            float2 v0 = x2[s0 * 64 + lane];
            ax = fmaf(v0.x, a0, ax); ay = fmaf(v0.y, a0, ay);
        }
    }
    float nd = rsqrtf((float)max(dg, 1));
    ((float2*)agg)[n * 64 + lane] = make_float2(ax * nd, ay * nd);
}

// ---------------------------------------------------------------------------
// K6: MFMA bf16 GEMM + NodeNorm + relu + residual (unchanged).
// ---------------------------------------------------------------------------
#define WT_STRIDE 136
#define H_STRIDE  132

__global__ __launch_bounds__(256, 2) void k_gemm_norm(
    const float* __restrict__ agg,
    const float* __restrict__ x,
    const float* __restrict__ W,
    const float* __restrict__ bias,
    float* __restrict__ out, int N)
{
    __shared__ char raw[D * WT_STRIDE * 2];           // 34816 B >= 64*132*4
    short* Wt = (short*)raw;                          // Wt[c][k], bf16
    float* h  = (float*)raw;                          // h[64][H_STRIDE], after

    const int t = threadIdx.x;
    const int lane = t & 63;
    const int w = t >> 6;
    const int row0 = blockIdx.x * 64;

    #pragma unroll 4
    for (int i = 0; i < 64; ++i) {
        int idx = t + i * 256;
        int k = idx >> 7, c = idx & 127;
        Wt[c * WT_STRIDE + k] = f32_bf16(W[idx]);
    }
    __syncthreads();

    const int col16 = lane & 15;
    const int quad  = lane >> 4;
    int arow = row0 + w * 16 + col16;
    if (arow >= N) arow = N - 1;
    const float* aptr = agg + (long long)arow * D + quad * 8;

    floatx4 acc[8];
    #pragma unroll
    for (int c = 0; c < 8; ++c) {
        float b = bias[c * 16 + col16];
        acc[c] = (floatx4){b, b, b, b};
    }

    #pragma unroll
    for (int kc = 0; kc < 4; ++kc) {
        float4 a0 = *(const float4*)(aptr + kc * 32);
        float4 a1 = *(const float4*)(aptr + kc * 32 + 4);
        short8 af;
        af[0] = f32_bf16(a0.x); af[1] = f32_bf16(a0.y);
        af[2] = f32_bf16(a0.z); af[3] = f32_bf16(a0.w);
        af[4] = f32_bf16(a1.x); af[5] = f32_bf16(a1.y);
        af[6] = f32_bf16(a1.z); af[7] = f32_bf16(a1.w);
        const short* wbase = Wt + kc * 32 + quad * 8;
        #pragma unroll
        for (int c = 0; c < 8; ++c) {
            short8 bf = *(const short8*)(wbase + (c * 16 + col16) * WT_STRIDE);
            acc[c] = __builtin_amdgcn_mfma_f32_16x16x32_bf16(af, bf, acc[c], 0, 0, 0);
        }
    }
    __syncthreads();

    #pragma unroll
    for (int c = 0; c < 8; ++c) {
        #pragma unroll
        for (int i = 0; i < 4; ++i) {
            h[(w * 16 + quad * 4 + i) * H_STRIDE + c * 16 + col16] = acc[c][i];
        }
    }
    __syncthreads();

    const int row = t >> 2;
    const int part = t & 3;
    const float* hp = h + row * H_STRIDE + part * 32;
    float4 hv[8];
    float s = 0.f, ss = 0.f;
    #pragma unroll
    for (int i = 0; i < 8; ++i) {
        float4 v = *(const float4*)(hp + i * 4);
        hv[i] = v;
        s  += v.x + v.y + v.z + v.w;
        ss += v.x * v.x + v.y * v.y + v.z * v.z + v.w * v.w;
    }
    s += __shfl_xor(s, 1); ss += __shfl_xor(ss, 1);
    s += __shfl_xor(s, 2); ss += __shfl_xor(ss, 2);
    const float mean = s * (1.0f / 128.0f);
    const float var = ss * (1.0f / 128.0f) - mean * mean;
    const float inv = rsqrtf(var + 1e-5f);
    const int grow = row0 + row;
    if (grow < N) {
        const float* xp = x + (long long)grow * D + part * 32;
        float* op = out + (long long)grow * D + part * 32;
        #pragma unroll
        for (int i = 0; i < 8; ++i) {
            float4 v = hv[i];
            float4 xr = *(const float4*)(xp + i * 4);
            float4 o;
            o.x = fmaxf((v.x - mean) * inv, 0.f) + xr.x;
            o.y = fmaxf((v.y - mean) * inv, 0.f) + xr.y;
            o.z = fmaxf((v.z - mean) * inv, 0.f) + xr.z;
            o.w = fmaxf((v.w - mean) * inv, 0.f) + xr.w;
            *(float4*)(op + i * 4) = o;
        }
    }
}

// ---------------------------------------------------------------------------
extern "C" void kernel_launch(void* const* d_in, const int* in_sizes, int n_in,
                              void* d_out, int out_size, void* d_ws, size_t ws_size,
                              hipStream_t stream) {
    const float* x    = (const float*)d_in[0];
    const float* W    = (const float*)d_in[1];
    const float* bias = (const float*)d_in[2];
    const int*   src  = (const int*)d_in[3];
    const int*   dst  = (const int*)d_in[4];
    const int N = in_sizes[0] / D;
    const int E = in_sizes[3];
    float* out = (float*)d_out;

    auto al = [](size_t b) { return (b + 255) & ~(size_t)255; };
    size_t inrep_b  = al((size_t)8 * N * 4);
    size_t outrep_b = al((size_t)8 * N * 4);
    size_t wcnt_b   = al((size_t)N * 4);
    size_t ctrl_b   = 256;
    size_t base_b   = al((size_t)N * 4);
    size_t deg_b    = al((size_t)N * 4);
    size_t nsrc_b   = al((size_t)N * 4);
    size_t csr_b    = al((size_t)E * 4);
    size_t xb_b     = al((size_t)N * D * 2);

    size_t need_core = inrep_b + outrep_b + wcnt_b + ctrl_b + base_b + deg_b +
                       nsrc_b + csr_b;
    bool use_bf = (ws_size >= need_core + xb_b);

    char* p = (char*)d_ws;
    int*   inrep  = (int*)p;     p += inrep_b;   // ── zeroed region start
    int*   outrep = (int*)p;     p += outrep_b;
    int*   wcnt   = (int*)p;     p += wcnt_b;
    int*   ctrl   = (int*)p;     p += ctrl_b;    // ── zeroed region end
    int*   base   = (int*)p;     p += base_b;
    int*   deg    = (int*)p;     p += deg_b;
    float* nsrc   = (float*)p;   p += nsrc_b;
    int*   csr    = (int*)p;     p += csr_b;
    unsigned short* xb = (unsigned short*)p;

    float* agg = out;      // alias output as aggregation buffer

    hipMemsetAsync(inrep, 0, inrep_b + outrep_b + wcnt_b + ctrl_b, stream);

    const int nv4 = E >> 2;
    const int EB4 = (nv4 + 255) / 256 + 1;   // covers vector part + tail
    const int NB  = (N + 255) / 256;

    k_hist<<<EB4, 256, 0, stream>>>(src, dst, outrep, inrep, E, N);
    k_base<<<NB, 256, 0, stream>>>(inrep, outrep, base, deg, nsrc, ctrl, N);
    if (use_bf) {
        int n8 = N * D / 8;
        k_cvt<<<(n8 + 255) / 256, 256, 0, stream>>>(x, xb, n8);
    }
    const unsigned int* xbp = use_bf ? (const unsigned int*)xb : nullptr;

    k_scatter<<<EB4, 256, 0, stream>>>(src, dst, base, wcnt, csr, E);
    k_agg<<<(N + 3) / 4, 256, 0, stream>>>(csr, base, deg, nsrc, xbp, x, agg, N);
    k_gemm_norm<<<(N + 63) / 64, 256, 0, stream>>>(agg, x, W, bias, out, N);
}